// Round 1
// baseline (493.820 us; speedup 1.0000x reference)
//
#include <hip/hip_runtime.h>
#include <math.h>

#define KTHREADS 256
#define QB 4                       // queries per KNN block
#define NBUCKET 2048
#define CHUNK (NBUCKET / KTHREADS) // 8
#define CANDMAX 256
#define TSAMP 12u
#define EPS_KNN 1e-12f
#define EPS_COS 1e-8f

__device__ __forceinline__ float wredf(float v) {
#pragma unroll
    for (int off = 32; off > 0; off >>= 1) v += __shfl_xor(v, off, 64);
    return v;
}

// ---------------- MLP: x_dot = MLP([x, t]) ----------------
// 128 threads (2 waves), 8 queries/block, each wave owns 4 queries,
// each lane owns 8 output columns (c0..c0+3, c0+256..c0+259).
__global__ __launch_bounds__(128) void mlp_kernel(
    const float* __restrict__ z, const float* __restrict__ tp,
    const float* __restrict__ W1, const float* __restrict__ b1,
    const float* __restrict__ W2, const float* __restrict__ b2,
    const float* __restrict__ W3, const float* __restrict__ b3,
    float* __restrict__ xdot, int B)
{
    __shared__ float h1[8][512];
    const int tid = threadIdx.x;
    const int lane = tid & 63;
    const int wid = tid >> 6; // 0..1
    const int qbase = blockIdx.x * 8;
    const float t = tp[0];

    for (int idx = tid; idx < 8 * 512; idx += 128) {
        const int q = idx >> 9, j = idx & 511;
        const int qid = qbase + q;
        float v = 0.f;
        if (qid < B) {
            const float a = z[qid * 6 + 0], b = z[qid * 6 + 1], c = z[qid * 6 + 2];
            v = fmaf(a, W1[j], fmaf(b, W1[512 + j], fmaf(c, W1[1024 + j], fmaf(t, W1[1536 + j], b1[j]))));
            v = fmaxf(v, 0.f);
        }
        h1[q][j] = v;
    }
    __syncthreads();

    const int c0 = lane * 4;
    const int qw = wid * 4;
    float acc[4][8];
#pragma unroll
    for (int q = 0; q < 4; ++q) {
#pragma unroll
        for (int c = 0; c < 4; ++c) {
            acc[q][c]     = b2[c0 + c];
            acc[q][4 + c] = b2[c0 + 256 + c];
        }
    }
    for (int i = 0; i < 512; i += 4) {
        float4 hv[4];
#pragma unroll
        for (int q = 0; q < 4; ++q) hv[q] = *(const float4*)&h1[qw + q][i];
#pragma unroll
        for (int u = 0; u < 4; ++u) {
            const float* wr = W2 + (i + u) * 512;
            const float4 wA = *(const float4*)(wr + c0);
            const float4 wB = *(const float4*)(wr + c0 + 256);
#pragma unroll
            for (int q = 0; q < 4; ++q) {
                const float h = (u == 0) ? hv[q].x : (u == 1) ? hv[q].y : (u == 2) ? hv[q].z : hv[q].w;
                acc[q][0] = fmaf(h, wA.x, acc[q][0]);
                acc[q][1] = fmaf(h, wA.y, acc[q][1]);
                acc[q][2] = fmaf(h, wA.z, acc[q][2]);
                acc[q][3] = fmaf(h, wA.w, acc[q][3]);
                acc[q][4] = fmaf(h, wB.x, acc[q][4]);
                acc[q][5] = fmaf(h, wB.y, acc[q][5]);
                acc[q][6] = fmaf(h, wB.z, acc[q][6]);
                acc[q][7] = fmaf(h, wB.w, acc[q][7]);
            }
        }
    }
#pragma unroll
    for (int q = 0; q < 4; ++q) {
        float p0 = 0.f, p1 = 0.f, p2 = 0.f;
#pragma unroll
        for (int c = 0; c < 8; ++c) {
            const int col = (c < 4) ? (c0 + c) : (c0 + 252 + c); // c>=4 -> c0+256+(c-4)
            const float h = fmaxf(acc[q][c], 0.f);
            p0 = fmaf(h, W3[col * 3 + 0], p0);
            p1 = fmaf(h, W3[col * 3 + 1], p1);
            p2 = fmaf(h, W3[col * 3 + 2], p2);
        }
        p0 = wredf(p0); p1 = wredf(p1); p2 = wredf(p2);
        const int qid = qbase + qw + q;
        if (lane == 0 && qid < B) {
            xdot[qid * 3 + 0] = p0 + b3[0];
            xdot[qid * 3 + 1] = p1 + b3[1];
            xdot[qid * 3 + 2] = p2 + b3[2];
        }
    }
}

// Block-cooperative: smallest bucket b with cum(hist[0..b]) >= T.
// Results via LDS (*out_b = -1 if total < T). Ends with __syncthreads().
__device__ void scan_find(const unsigned int* h, unsigned int T,
                          int* out_b, unsigned int* out_total,
                          unsigned int* wtot, int tid)
{
    const int lane = tid & 63, wid = tid >> 6;
    const int base = tid * CHUNK;
    unsigned int s = 0;
#pragma unroll
    for (int u = 0; u < CHUNK; ++u) s += h[base + u];
    unsigned int incl = s;
#pragma unroll
    for (int d = 1; d < 64; d <<= 1) {
        unsigned int n = (unsigned int)__shfl_up((int)incl, d, 64);
        if (lane >= d) incl += n;
    }
    if (tid == 0) *out_b = -1;
    if (lane == 63) wtot[wid] = incl;
    __syncthreads();
    unsigned int offs = 0;
    for (int w = 0; w < wid; ++w) offs += wtot[w];
    const unsigned int total = wtot[0] + wtot[1] + wtot[2] + wtot[3];
    const unsigned int excl = offs + (incl - s);
    if (excl < T && T <= excl + s) {
        unsigned int c = excl;
        for (int u = 0; u < CHUNK; ++u) {
            c += h[base + u];
            if (c >= T) { *out_b = base + u; break; }
        }
    }
    if (tid == 0) *out_total = total;
    __syncthreads();
}

// ---------------- KNN + final metrics ----------------
__global__ __launch_bounds__(KTHREADS) void knn_kernel(
    const float* __restrict__ z,
    const float* __restrict__ x0, const float* __restrict__ x1,
    const float* __restrict__ v0, const float* __restrict__ v1,
    const float* __restrict__ xdot, const int* __restrict__ kp,
    float* __restrict__ out, int B, int N0, int N1)
{
    const int N = N0 + N1;
    const unsigned int K = (unsigned int)kp[0];

    __shared__ unsigned int hist[QB][NBUCKET];
    __shared__ float candD[QB][CANDMAX];
    __shared__ int   candI[QB][CANDMAX];
    __shared__ unsigned int candCnt[QB];
    __shared__ float capv[QB], scalev[QB];
    __shared__ int   bselv[QB];
    __shared__ float hselv[QB];
    __shared__ int   iselv[QB];
    __shared__ unsigned int wtot[4];
    __shared__ int s_b;
    __shared__ unsigned int s_tot;
    __shared__ int sflag;
    __shared__ float qsh[QB][4];
    __shared__ float redbuf[4][QB * 4];

    const int tid = threadIdx.x, lane = tid & 63, wid = tid >> 6;
    const int qbase = blockIdx.x * QB;

    if (tid < QB) {
        const int qid = qbase + tid;
        float a = 0.f, b = 0.f, c = 0.f;
        if (qid < B) { a = z[qid * 6 + 0]; b = z[qid * 6 + 1]; c = z[qid * 6 + 2]; }
        qsh[tid][0] = a; qsh[tid][1] = b; qsh[tid][2] = c;
        qsh[tid][3] = fmaf(a, a, fmaf(b, b, c * c));
    }
    for (int i = tid; i < QB * NBUCKET; i += KTHREADS) (&hist[0][0])[i] = 0u;
    __syncthreads();

    float qx[QB], qy[QB], qz[QB], q2[QB];
#pragma unroll
    for (int q = 0; q < QB; ++q) { qx[q] = qsh[q][0]; qy[q] = qsh[q][1]; qz[q] = qsh[q][2]; q2[q] = qsh[q][3]; }

    // full-sweep helper: fn(q, point_index, d2_clamped); d2 math is the SAME
    // instruction sequence at every use -> bit-identical across passes.
    auto sweepAll = [&](auto&& fn) {
        for (int j = tid; j < N0; j += KTHREADS) {
            const float px = x0[3 * j], py = x0[3 * j + 1], pz = x0[3 * j + 2];
            const float p2 = fmaf(px, px, fmaf(py, py, pz * pz));
#pragma unroll
            for (int q = 0; q < QB; ++q) {
                const float dt = fmaf(qx[q], px, fmaf(qy[q], py, qz[q] * pz));
                const float d2 = fmaf(-2.f, dt, q2[q] + p2);
                fn(q, j, fmaxf(d2, 0.f));
            }
        }
        for (int jj = tid; jj < N1; jj += KTHREADS) {
            const float px = x1[3 * jj], py = x1[3 * jj + 1], pz = x1[3 * jj + 2];
            const float p2 = fmaf(px, px, fmaf(py, py, pz * pz));
#pragma unroll
            for (int q = 0; q < QB; ++q) {
                const float dt = fmaf(qx[q], px, fmaf(qy[q], py, qz[q] * pz));
                const float d2 = fmaf(-2.f, dt, q2[q] + p2);
                fn(q, N0 + jj, fmaxf(d2, 0.f));
            }
        }
    };

    // ---- sample phase: coarse (exponent|3-mantissa-bit) histogram of 2048 samples
    for (int s = tid; s < 2048; s += KTHREADS) {
        const int j = (int)(((long long)s * (long long)N) >> 11);
        float px, py, pz;
        if (j < N0) { px = x0[3 * j]; py = x0[3 * j + 1]; pz = x0[3 * j + 2]; }
        else { const int j2 = j - N0; px = x1[3 * j2]; py = x1[3 * j2 + 1]; pz = x1[3 * j2 + 2]; }
        const float p2 = fmaf(px, px, fmaf(py, py, pz * pz));
#pragma unroll
        for (int q = 0; q < QB; ++q) {
            const float dt = fmaf(qx[q], px, fmaf(qy[q], py, qz[q] * pz));
            float d2 = fmaf(-2.f, dt, q2[q] + p2);
            d2 = fmaxf(d2, 0.f);
            int bu = (int)(__float_as_uint(d2) >> 20);
            bu = bu < (NBUCKET - 1) ? bu : (NBUCKET - 1);
            atomicAdd(&hist[q][bu], 1u);
        }
    }
    __syncthreads();
    for (int q = 0; q < QB; ++q) {
        scan_find(&hist[q][0], TSAMP, &s_b, &s_tot, wtot, tid);
        if (tid == 0) {
            int b = s_b; if (b < 0) b = NBUCKET - 1;
            const unsigned int ub = (unsigned int)(b + 1);
            const float cap = (ub >= 2040u) ? 3.4e38f : __uint_as_float(ub << 20);
            capv[q] = cap;
            scalev[q] = (float)NBUCKET / cap;
        }
        __syncthreads();
    }

    // ---- fine histogram over [0, cap) with retry if cap was too small
    for (int attempt = 0; attempt < 3; ++attempt) {
        if (tid == 0) sflag = 0;
        for (int i = tid; i < QB * NBUCKET; i += KTHREADS) (&hist[0][0])[i] = 0u;
        __syncthreads();
        {
            float rcap[QB], rsc[QB];
#pragma unroll
            for (int q = 0; q < QB; ++q) { rcap[q] = capv[q]; rsc[q] = scalev[q]; }
            sweepAll([&](int q, int j, float d2) {
                (void)j;
                if (d2 < rcap[q]) {
                    int bu = (int)(d2 * rsc[q]);
                    bu = bu < (NBUCKET - 1) ? bu : (NBUCKET - 1);
                    atomicAdd(&hist[q][bu], 1u);
                }
            });
        }
        __syncthreads();
        for (int q = 0; q < QB; ++q) {
            scan_find(&hist[q][0], K, &s_b, &s_tot, wtot, tid);
            if (tid == 0) {
                if (s_tot < K) { capv[q] *= 256.f; scalev[q] = (float)NBUCKET / capv[q]; sflag = 1; }
                else bselv[q] = s_b;
            }
            __syncthreads();
        }
        if (!sflag) break;
    }

    // ---- collect all candidates in buckets <= bsel (superset of the k nearest)
    if (tid < QB) candCnt[tid] = 0u;
    __syncthreads();
    {
        float rcap[QB], rsc[QB]; int rb[QB];
#pragma unroll
        for (int q = 0; q < QB; ++q) { rcap[q] = capv[q]; rsc[q] = scalev[q]; rb[q] = bselv[q]; }
        sweepAll([&](int q, int j, float d2) {
            if (d2 < rcap[q]) {
                int bu = (int)(d2 * rsc[q]);
                bu = bu < (NBUCKET - 1) ? bu : (NBUCKET - 1);
                if (bu <= rb[q]) {
                    const unsigned int pos = atomicAdd(&candCnt[q], 1u);
                    if (pos < CANDMAX) { candD[q][pos] = sqrtf(d2); candI[q][pos] = j; }
                }
            }
        });
    }
    __syncthreads();

    // ---- exact rank (dist, idx) lexicographic -> kth distance h (matches top_k ties)
    for (int q = 0; q < QB; ++q) {
        const int m = (int)(candCnt[q] < (unsigned int)CANDMAX ? candCnt[q] : (unsigned int)CANDMAX);
        for (int i = tid; i < m; i += KTHREADS) {
            const float di = candD[q][i];
            const int ii = candI[q][i];
            int r = 0;
            for (int jc = 0; jc < m; ++jc) {
                const float dj = candD[q][jc];
                if (dj < di || (dj == di && candI[q][jc] < ii)) ++r;
            }
            if (r == (int)K - 1) { hselv[q] = di; iselv[q] = ii; }
        }
    }
    __syncthreads();

    // ---- weighted accumulation over the exact k selected
    for (int q = 0; q < QB; ++q) {
        const float hS = hselv[q];
        const int iS = iselv[q];
        const float hcl = fmaxf(hS, EPS_KNN);
        const float inv2h2 = 1.f / (2.f * hcl * hcl);
        const int m = (int)(candCnt[q] < (unsigned int)CANDMAX ? candCnt[q] : (unsigned int)CANDMAX);
        float ws = 0.f, ax = 0.f, ay = 0.f, az = 0.f;
        for (int i = tid; i < m; i += KTHREADS) {
            const float s = candD[q][i];
            const int j = candI[q][i];
            if (s < hS || (s == hS && j <= iS)) {
                const float w = expf(-(s * s) * inv2h2);
                const float* vp = (j < N0) ? (v0 + 3 * (size_t)j) : (v1 + 3 * (size_t)(j - N0));
                ws += w;
                ax = fmaf(w, vp[0], ax);
                ay = fmaf(w, vp[1], ay);
                az = fmaf(w, vp[2], az);
            }
        }
        ws = wredf(ws); ax = wredf(ax); ay = wredf(ay); az = wredf(az);
        if (lane == 0) {
            redbuf[wid][q * 4 + 0] = ws; redbuf[wid][q * 4 + 1] = ax;
            redbuf[wid][q * 4 + 2] = ay; redbuf[wid][q * 4 + 3] = az;
        }
    }
    __syncthreads();

    if (tid < QB) {
        const int q = tid, qid = qbase + q;
        if (qid < B) {
            const float ws = redbuf[0][q*4+0] + redbuf[1][q*4+0] + redbuf[2][q*4+0] + redbuf[3][q*4+0];
            const float ax = redbuf[0][q*4+1] + redbuf[1][q*4+1] + redbuf[2][q*4+1] + redbuf[3][q*4+1];
            const float ay = redbuf[0][q*4+2] + redbuf[1][q*4+2] + redbuf[2][q*4+2] + redbuf[3][q*4+2];
            const float az = redbuf[0][q*4+3] + redbuf[1][q*4+3] + redbuf[2][q*4+3] + redbuf[3][q*4+3];
            const float inv = 1.f / (ws + EPS_KNN);
            const float ux = ax * inv, uy = ay * inv, uz = az * inv;
            const float d0 = xdot[qid * 3 + 0], d1 = xdot[qid * 3 + 1], d2v = xdot[qid * 3 + 2];
            const float nu = fmaxf(sqrtf(ux * ux + uy * uy + uz * uz), EPS_COS);
            const float nd = fmaxf(sqrtf(d0 * d0 + d1 * d1 + d2v * d2v), EPS_COS);
            const float cs = 1.f - (ux * d0 + uy * d1 + uz * d2v) / (nu * nd);
            const float ex = ux - d0, ey = uy - d1, ez = uz - d2v;
            const float l2 = ex * ex + ey * ey + ez * ez;
            out[qid * 6 + 0] = d0;
            out[qid * 6 + 1] = d1;
            out[qid * 6 + 2] = d2v;
            out[qid * 6 + 3] = cs;
            out[qid * 6 + 4] = cs;
            out[qid * 6 + 5] = l2;
        }
    }
}

extern "C" void kernel_launch(void* const* d_in, const int* in_sizes, int n_in,
                              void* d_out, int out_size, void* d_ws, size_t ws_size,
                              hipStream_t stream)
{
    const float* z  = (const float*)d_in[0];
    const float* tp = (const float*)d_in[1];
    const float* x0 = (const float*)d_in[2];
    const float* x1 = (const float*)d_in[3];
    const float* v0 = (const float*)d_in[4];
    const float* v1 = (const float*)d_in[5];
    const float* W1 = (const float*)d_in[6];
    const float* b1 = (const float*)d_in[7];
    const float* W2 = (const float*)d_in[8];
    const float* b2 = (const float*)d_in[9];
    const float* W3 = (const float*)d_in[10];
    const float* b3 = (const float*)d_in[11];
    const int*   kp = (const int*)d_in[12];
    float* outp = (float*)d_out;
    const int B  = in_sizes[0] / 6;
    const int N0 = in_sizes[2] / 3;
    const int N1 = in_sizes[3] / 3;
    float* xdot = (float*)d_ws;  // B*3 floats

    hipLaunchKernelGGL(mlp_kernel, dim3((B + 7) / 8), dim3(128), 0, stream,
                       z, tp, W1, b1, W2, b2, W3, b3, xdot, B);
    hipLaunchKernelGGL(knn_kernel, dim3((B + QB - 1) / QB), dim3(KTHREADS), 0, stream,
                       z, x0, x1, v0, v1, xdot, kp, outp, B, N0, N1);
}

// Round 3
// 278.372 us; speedup vs baseline: 1.7740x; 1.7740x over previous
//
#include <hip/hip_runtime.h>
#include <math.h>

#define KTHREADS 256
#define QB 2                       // queries per KNN block
#define NBUCKET 2048
#define CANDMAX 1024
#define TINY 256
#define TSAMP 8u
#define EPS_KNN 1e-12f
#define EPS_COS 1e-8f
#define MQ 8                       // queries per MLP block

__device__ __forceinline__ float wredf(float v) {
#pragma unroll
    for (int off = 32; off > 0; off >>= 1) v += __shfl_xor(v, off, 64);
    return v;
}
__device__ __forceinline__ unsigned int wredu(unsigned int v) {
#pragma unroll
    for (int off = 32; off > 0; off >>= 1) v += (unsigned int)__shfl_xor((int)v, off, 64);
    return v;
}

// ---------------- MLP: x_dot = MLP([x, t]) ----------------
// 512 threads (8 waves), MQ=8 queries/block. Wave w owns W2 columns
// [64w, 64w+64); lane owns a single column for ALL 8 queries -> every W2
// element is read exactly once per block (256 MB total L2 traffic).
__global__ __launch_bounds__(512) void mlp_kernel(
    const float* __restrict__ z, const float* __restrict__ tp,
    const float* __restrict__ W1, const float* __restrict__ b1,
    const float* __restrict__ W2, const float* __restrict__ b2,
    const float* __restrict__ W3, const float* __restrict__ b3,
    float* __restrict__ xdot, int B)
{
    __shared__ float h1[MQ][512];
    __shared__ float red[8][MQ * 3];
    const int tid = threadIdx.x, lane = tid & 63, wid = tid >> 6;
    const int qbase = blockIdx.x * MQ;
    const float t = tp[0];

    for (int idx = tid; idx < MQ * 512; idx += 512) {
        const int q = idx >> 9, j = idx & 511;
        const int qid = qbase + q;
        float v = 0.f;
        if (qid < B) {
            const float a = z[qid * 6 + 0], b = z[qid * 6 + 1], c = z[qid * 6 + 2];
            v = fmaf(a, W1[j], fmaf(b, W1[512 + j], fmaf(c, W1[1024 + j], fmaf(t, W1[1536 + j], b1[j]))));
            v = fmaxf(v, 0.f);
        }
        h1[q][j] = v;
    }
    __syncthreads();

    const int col = wid * 64 + lane;
    float acc[MQ];
#pragma unroll
    for (int q = 0; q < MQ; ++q) acc[q] = b2[col];
    for (int r = 0; r < 512; r += 4) {
        float4 hv[MQ];
#pragma unroll
        for (int q = 0; q < MQ; ++q) hv[q] = *(const float4*)&h1[q][r];
        const float w0 = W2[(r + 0) * 512 + col];
        const float w1 = W2[(r + 1) * 512 + col];
        const float w2 = W2[(r + 2) * 512 + col];
        const float w3 = W2[(r + 3) * 512 + col];
#pragma unroll
        for (int q = 0; q < MQ; ++q) {
            acc[q] = fmaf(hv[q].x, w0, acc[q]);
            acc[q] = fmaf(hv[q].y, w1, acc[q]);
            acc[q] = fmaf(hv[q].z, w2, acc[q]);
            acc[q] = fmaf(hv[q].w, w3, acc[q]);
        }
    }
    const float wc0 = W3[col * 3 + 0], wc1 = W3[col * 3 + 1], wc2 = W3[col * 3 + 2];
#pragma unroll
    for (int q = 0; q < MQ; ++q) {
        const float h = fmaxf(acc[q], 0.f);
        float p0 = h * wc0, p1 = h * wc1, p2 = h * wc2;
        p0 = wredf(p0); p1 = wredf(p1); p2 = wredf(p2);
        if (lane == 0) { red[wid][q * 3 + 0] = p0; red[wid][q * 3 + 1] = p1; red[wid][q * 3 + 2] = p2; }
    }
    __syncthreads();
    if (tid < MQ * 3) {
        const int q = tid / 3, d = tid % 3;
        float s = 0.f;
#pragma unroll
        for (int w = 0; w < 8; ++w) s += red[w][q * 3 + d];
        const int qid = qbase + q;
        if (qid < B) xdot[qid * 3 + d] = s + b3[d];
    }
}

// Block-cooperative: smallest bucket b with cum(h[0..b]) >= T.
// *out_b = -1 if total < T. Ends with __syncthreads().
template<int NB>
__device__ void scan_find(const unsigned int* h, unsigned int T,
                          int* out_b, unsigned int* out_total,
                          unsigned int* wtot, int tid)
{
    constexpr int CH = NB / KTHREADS;
    const int lane = tid & 63, wid = tid >> 6;
    const int base = tid * CH;
    unsigned int s = 0;
#pragma unroll
    for (int u = 0; u < CH; ++u) s += h[base + u];
    unsigned int incl = s;
#pragma unroll
    for (int d = 1; d < 64; d <<= 1) {
        unsigned int n = (unsigned int)__shfl_up((int)incl, d, 64);
        if (lane >= d) incl += n;
    }
    if (tid == 0) *out_b = -1;
    if (lane == 63) wtot[wid] = incl;
    __syncthreads();
    unsigned int offs = 0;
    for (int w = 0; w < wid; ++w) offs += wtot[w];
    const unsigned int total = wtot[0] + wtot[1] + wtot[2] + wtot[3];
    const unsigned int excl = offs + (incl - s);
    if (excl < T && T <= excl + s) {
        unsigned int c = excl;
        for (int u = 0; u < CH; ++u) {
            c += h[base + u];
            if (c >= T) { *out_b = base + u; break; }
        }
    }
    if (tid == 0) *out_total = total;
    __syncthreads();
}

// ---------------- KNN + final metrics ----------------
__global__ __launch_bounds__(KTHREADS) void knn_kernel(
    const float* __restrict__ z,
    const float* __restrict__ x0, const float* __restrict__ x1,
    const float* __restrict__ v0, const float* __restrict__ v1,
    const float* __restrict__ xdot, const int* __restrict__ kp,
    float* __restrict__ out, int B, int N0, int N1)
{
    const int N = N0 + N1;
    const unsigned int K = (unsigned int)kp[0];

    __shared__ unsigned int hist[QB][NBUCKET];   // 16KB, aliased with cand buffers
    float (*candD)[CANDMAX] = (float (*)[CANDMAX])&hist[0][0];
    int   (*candI)[CANDMAX] = (int (*)[CANDMAX])((char*)&hist[0][0] + sizeof(float) * QB * CANDMAX);
    __shared__ unsigned int fh[256];
    __shared__ float tinyD[TINY];
    __shared__ int   tinyI[TINY];
    __shared__ unsigned int tcnt;
    __shared__ unsigned int candCnt[QB];
    __shared__ float capv[QB];
    __shared__ float hselv[QB];
    __shared__ int   iselv[QB];
    __shared__ int   doneQ[QB];
    __shared__ int   anyleft;
    __shared__ unsigned int wtot[4];
    __shared__ int s_b;
    __shared__ unsigned int s_tot;
    __shared__ float qsh[QB][4];
    __shared__ float redbuf[4][QB * 4];

    const int tid = threadIdx.x, lane = tid & 63, wid = tid >> 6;
    const int qbase = blockIdx.x * QB;

    if (tid < QB) {
        const int qid = qbase + tid;
        float a = 0.f, b = 0.f, c = 0.f;
        if (qid < B) { a = z[qid * 6 + 0]; b = z[qid * 6 + 1]; c = z[qid * 6 + 2]; }
        qsh[tid][0] = a; qsh[tid][1] = b; qsh[tid][2] = c;
        qsh[tid][3] = fmaf(a, a, fmaf(b, b, c * c));
    }
    for (int i = tid; i < QB * NBUCKET; i += KTHREADS) (&hist[0][0])[i] = 0u;
    __syncthreads();

    float qx[QB], qy[QB], qz[QB], q2[QB];
#pragma unroll
    for (int q = 0; q < QB; ++q) { qx[q] = qsh[q][0]; qy[q] = qsh[q][1]; qz[q] = qsh[q][2]; q2[q] = qsh[q][3]; }

    // full-sweep: fn(q, idx, d2_clamped). d2 math identical at every use.
    auto sweepAll = [&](auto&& fn) {
        auto doPoint = [&](float px, float py, float pz, int idx) {
            const float p2 = fmaf(px, px, fmaf(py, py, pz * pz));
#pragma unroll
            for (int q = 0; q < QB; ++q) {
                const float dt = fmaf(qx[q], px, fmaf(qy[q], py, qz[q] * pz));
                const float d2 = fmaf(-2.f, dt, q2[q] + p2);
                fn(q, idx, fmaxf(d2, 0.f));
            }
        };
        const int G0 = N0 >> 2;
        for (int g = tid; g < G0; g += KTHREADS) {
            const float4* bp = (const float4*)(x0 + 12 * (size_t)g);
            const float4 A = bp[0], Bv = bp[1], C = bp[2];
            doPoint(A.x, A.y, A.z, 4 * g + 0);
            doPoint(A.w, Bv.x, Bv.y, 4 * g + 1);
            doPoint(Bv.z, Bv.w, C.x, 4 * g + 2);
            doPoint(C.y, C.z, C.w, 4 * g + 3);
        }
        for (int j = (G0 << 2) + tid; j < N0; j += KTHREADS) {
            doPoint(x0[3 * j], x0[3 * j + 1], x0[3 * j + 2], j);
        }
        const int G1 = N1 >> 2;
        for (int g = tid; g < G1; g += KTHREADS) {
            const float4* bp = (const float4*)(x1 + 12 * (size_t)g);
            const float4 A = bp[0], Bv = bp[1], C = bp[2];
            doPoint(A.x, A.y, A.z, N0 + 4 * g + 0);
            doPoint(A.w, Bv.x, Bv.y, N0 + 4 * g + 1);
            doPoint(Bv.z, Bv.w, C.x, N0 + 4 * g + 2);
            doPoint(C.y, C.z, C.w, N0 + 4 * g + 3);
        }
        for (int j = (G1 << 2) + tid; j < N1; j += KTHREADS) {
            doPoint(x1[3 * j], x1[3 * j + 1], x1[3 * j + 2], N0 + j);
        }
    };

    // ---- sample phase: coarse (exponent|3-mantissa-bit) histogram of 2048 samples
    for (int s = tid; s < 2048; s += KTHREADS) {
        const int j = (int)(((long long)s * (long long)N) >> 11);
        float px, py, pz;
        if (j < N0) { px = x0[3 * j]; py = x0[3 * j + 1]; pz = x0[3 * j + 2]; }
        else { const int j2 = j - N0; px = x1[3 * j2]; py = x1[3 * j2 + 1]; pz = x1[3 * j2 + 2]; }
        const float p2 = fmaf(px, px, fmaf(py, py, pz * pz));
#pragma unroll
        for (int q = 0; q < QB; ++q) {
            const float dt = fmaf(qx[q], px, fmaf(qy[q], py, qz[q] * pz));
            float d2 = fmaf(-2.f, dt, q2[q] + p2);
            d2 = fmaxf(d2, 0.f);
            int bu = (int)(__float_as_uint(d2) >> 20);
            bu = bu < (NBUCKET - 1) ? bu : (NBUCKET - 1);
            atomicAdd(&hist[q][bu], 1u);
        }
    }
    __syncthreads();
    for (int q = 0; q < QB; ++q) {
        scan_find<NBUCKET>(&hist[q][0], TSAMP, &s_b, &s_tot, wtot, tid);
        if (tid == 0) {
            int b = s_b; if (b < 0) b = NBUCKET - 1;
            const unsigned int ub = (unsigned int)(b + 1);
            const float cap = (ub >= 2040u) ? 3.4e38f : __uint_as_float(ub << 20);
            capv[q] = (qbase + q < B) ? cap : -1.f;
            doneQ[q] = (qbase + q < B) ? 0 : 1;
        }
        __syncthreads();
    }

    // ---- single collect sweep (rare count-based retries, per-query masked)
    for (int attempt = 0; attempt < 4; ++attempt) {
        if (tid == 0) anyleft = 0;
        if (tid < QB && !doneQ[tid]) candCnt[tid] = 0u;
        __syncthreads();
        float rcap[QB];
#pragma unroll
        for (int q = 0; q < QB; ++q) rcap[q] = doneQ[q] ? -1.f : capv[q];
        sweepAll([&](int q, int j, float d2) {
            if (d2 < rcap[q]) {
                const unsigned int pos = atomicAdd(&candCnt[q], 1u);
                if (pos < (unsigned int)CANDMAX) { candD[q][pos] = sqrtf(d2); candI[q][pos] = j; }
            }
        });
        __syncthreads();
        if (tid < QB && !doneQ[tid]) {
            const unsigned int c = candCnt[tid];
            if (c >= K && c <= (unsigned int)CANDMAX) doneQ[tid] = 1;
            else {
                const unsigned int cc = c < 8u ? 8u : c;
                capv[tid] *= __powf(384.f / (float)cc, 0.6666667f);
                anyleft = 1;
            }
        }
        __syncthreads();
        if (!anyleft) break;
    }

    // ---- exact k-th via 256-bin candidate histogram + tiny lexicographic rank
    for (int q = 0; q < QB; ++q) {
        if (qbase + q >= B) continue;
        const unsigned int cnt = candCnt[q];
        const int m = (int)(cnt < (unsigned int)CANDMAX ? cnt : (unsigned int)CANDMAX);
        fh[tid] = 0u;
        __syncthreads();
        const float sc = 256.f / sqrtf(capv[q]);
        for (int i = tid; i < m; i += KTHREADS) {
            int b = (int)(candD[q][i] * sc); b = b < 255 ? b : 255;
            atomicAdd(&fh[b], 1u);
        }
        __syncthreads();
        scan_find<256>(fh, K, &s_b, &s_tot, wtot, tid);
        const int bsel = s_b < 0 ? 255 : s_b;
        unsigned int v = (tid < bsel) ? fh[tid] : 0u;
        v = wredu(v);
        if (lane == 0) wtot[wid] = v;
        if (tid == 0) tcnt = 0u;
        __syncthreads();
        const unsigned int Cb = wtot[0] + wtot[1] + wtot[2] + wtot[3];
        for (int i = tid; i < m; i += KTHREADS) {
            int b = (int)(candD[q][i] * sc); b = b < 255 ? b : 255;
            if (b == bsel) {
                const unsigned int p = atomicAdd(&tcnt, 1u);
                if (p < (unsigned int)TINY) { tinyD[p] = candD[q][i]; tinyI[p] = candI[q][i]; }
            }
        }
        __syncthreads();
        const int c2 = (int)tcnt;
        const int need = (int)K - 1 - (int)Cb;
        if (c2 <= TINY) {
            for (int i = tid; i < c2; i += KTHREADS) {
                const float di = tinyD[i]; const int ii = tinyI[i];
                int r = 0;
                for (int j2 = 0; j2 < c2; ++j2) {
                    const float dj = tinyD[j2];
                    if (dj < di || (dj == di && tinyI[j2] < ii)) ++r;
                }
                if (r == need) { hselv[q] = di; iselv[q] = ii; }
            }
        } else {
            for (int i = tid; i < m; i += KTHREADS) {
                const float di = candD[q][i]; const int ii = candI[q][i];
                int r = 0;
                for (int j2 = 0; j2 < m; ++j2) {
                    const float dj = candD[q][j2];
                    if (dj < di || (dj == di && candI[q][j2] < ii)) ++r;
                }
                if (r == (int)K - 1) { hselv[q] = di; iselv[q] = ii; }
            }
        }
        __syncthreads();
    }

    // ---- weighted accumulation over the exact k selected
    for (int q = 0; q < QB; ++q) {
        if (qbase + q >= B) continue;
        const float hS = hselv[q];
        const int iS = iselv[q];
        const float hcl = fmaxf(hS, EPS_KNN);
        const float inv2h2 = 1.f / (2.f * hcl * hcl);
        const unsigned int cnt = candCnt[q];
        const int m = (int)(cnt < (unsigned int)CANDMAX ? cnt : (unsigned int)CANDMAX);
        float ws = 0.f, ax = 0.f, ay = 0.f, az = 0.f;
        for (int i = tid; i < m; i += KTHREADS) {
            const float s = candD[q][i];
            const int j = candI[q][i];
            if (s < hS || (s == hS && j <= iS)) {
                const float w = expf(-(s * s) * inv2h2);
                const float* vp = (j < N0) ? (v0 + 3 * (size_t)j) : (v1 + 3 * (size_t)(j - N0));
                ws += w;
                ax = fmaf(w, vp[0], ax);
                ay = fmaf(w, vp[1], ay);
                az = fmaf(w, vp[2], az);
            }
        }
        ws = wredf(ws); ax = wredf(ax); ay = wredf(ay); az = wredf(az);
        if (lane == 0) {
            redbuf[wid][q * 4 + 0] = ws; redbuf[wid][q * 4 + 1] = ax;
            redbuf[wid][q * 4 + 2] = ay; redbuf[wid][q * 4 + 3] = az;
        }
    }
    __syncthreads();

    if (tid < QB) {
        const int q = tid, qid = qbase + q;
        if (qid < B) {
            const float ws = redbuf[0][q*4+0] + redbuf[1][q*4+0] + redbuf[2][q*4+0] + redbuf[3][q*4+0];
            const float ax = redbuf[0][q*4+1] + redbuf[1][q*4+1] + redbuf[2][q*4+1] + redbuf[3][q*4+1];
            const float ay = redbuf[0][q*4+2] + redbuf[1][q*4+2] + redbuf[2][q*4+2] + redbuf[3][q*4+2];
            const float az = redbuf[0][q*4+3] + redbuf[1][q*4+3] + redbuf[2][q*4+3] + redbuf[3][q*4+3];
            const float inv = 1.f / (ws + EPS_KNN);
            const float ux = ax * inv, uy = ay * inv, uz = az * inv;
            const float d0 = xdot[qid * 3 + 0], d1 = xdot[qid * 3 + 1], d2v = xdot[qid * 3 + 2];
            const float nu = fmaxf(sqrtf(ux * ux + uy * uy + uz * uz), EPS_COS);
            const float nd = fmaxf(sqrtf(d0 * d0 + d1 * d1 + d2v * d2v), EPS_COS);
            const float cs = 1.f - (ux * d0 + uy * d1 + uz * d2v) / (nu * nd);
            const float ex = ux - d0, ey = uy - d1, ez = uz - d2v;
            const float l2 = ex * ex + ey * ey + ez * ez;
            out[qid * 6 + 0] = d0;
            out[qid * 6 + 1] = d1;
            out[qid * 6 + 2] = d2v;
            out[qid * 6 + 3] = cs;
            out[qid * 6 + 4] = cs;
            out[qid * 6 + 5] = l2;
        }
    }
}

extern "C" void kernel_launch(void* const* d_in, const int* in_sizes, int n_in,
                              void* d_out, int out_size, void* d_ws, size_t ws_size,
                              hipStream_t stream)
{
    const float* z  = (const float*)d_in[0];
    const float* tp = (const float*)d_in[1];
    const float* x0 = (const float*)d_in[2];
    const float* x1 = (const float*)d_in[3];
    const float* v0 = (const float*)d_in[4];
    const float* v1 = (const float*)d_in[5];
    const float* W1 = (const float*)d_in[6];
    const float* b1 = (const float*)d_in[7];
    const float* W2 = (const float*)d_in[8];
    const float* b2 = (const float*)d_in[9];
    const float* W3 = (const float*)d_in[10];
    const float* b3 = (const float*)d_in[11];
    const int*   kp = (const int*)d_in[12];
    float* outp = (float*)d_out;
    const int B  = in_sizes[0] / 6;
    const int N0 = in_sizes[2] / 3;
    const int N1 = in_sizes[3] / 3;
    float* xdot = (float*)d_ws;  // B*3 floats

    hipLaunchKernelGGL(mlp_kernel, dim3((B + MQ - 1) / MQ), dim3(512), 0, stream,
                       z, tp, W1, b1, W2, b2, W3, b3, xdot, B);
    hipLaunchKernelGGL(knn_kernel, dim3((B + QB - 1) / QB), dim3(KTHREADS), 0, stream,
                       z, x0, x1, v0, v1, xdot, kp, outp, B, N0, N1);
}